// Round 6
// baseline (18.437 us; speedup 1.0000x reference)
//
#include <hip/hip_runtime.h>

// ROI max-pooling, TF-style integer binning (matches the JAX reference).
// Round 6: one BIN per 256-thread block (4 waves); bin columns strided
// across waves (w = clo + wid + 4k) + LDS cross-wave max -> bounds the
// critical wave at ~1/4 of the heaviest bin window (last-row/col bins can
// hit ~100 px). XCD pinning (image b -> XCD pair {2b,2b+1}) + nontemporal
// output store kept from R5.

#define OUT_H 7
#define OUT_W 7
#define NBIN (OUT_H * OUT_W)   // 49
#define NB 4
#define NR 64
#define NH 56
#define NW 56
#define NC 256
#define C4 (NC / 4)            // 64 float4 groups per pixel

// total bins = 4*64*49 = 12544 blocks; per image 3136; per XCD slot 1568
#define BLKS_PER_XCD_SLOT 1568

typedef float v4f __attribute__((ext_vector_type(4)));

__device__ __forceinline__ v4f vmax4(v4f a, v4f b) {
    v4f r;
    r.x = fmaxf(a.x, b.x);
    r.y = fmaxf(a.y, b.y);
    r.z = fmaxf(a.z, b.z);
    r.w = fmaxf(a.w, b.w);
    return r;
}

__global__ __launch_bounds__(256) void roi_pool_kernel(
    const float* __restrict__ fmap,   // [B,H,W,C]
    const float* __restrict__ rois,   // [B,R,4]
    float* __restrict__ out)          // [B,R,7,7,C]
{
    __shared__ v4f red[3][64];        // waves 1..3 deposit here

    const int blk  = blockIdx.x;
    const int xcd  = blk & 7;          // image b -> XCDs {2b, 2b+1}
    const int b    = xcd >> 1;
    const int wid  = threadIdx.x >> 6; // wave id 0..3 -> column stride slot
    const int lane = threadIdx.x & 63; // float4 channel group

    const int work = ((xcd & 1) * BLKS_PER_XCD_SLOT) + (blk >> 3); // [0,3136)
    const int r    = work / NBIN;
    const int bin  = work - r * NBIN;
    const int oi   = bin / OUT_W;
    const int oj   = bin - oi * OUT_W;

    const float* roi = rois + (size_t)(b * NR + r) * 4;
    const float r0 = roi[0], r1 = roi[1], r2 = roi[2], r3 = roi[3];
    const int h0 = (int)((float)NH * r0);
    const int w0 = (int)((float)NW * r1);
    const int h1 = (int)((float)NH * r2);
    const int w1 = (int)((float)NW * r3);

    const int hstep = (int)((float)(h1 - h0) / (float)OUT_H);
    const int wstep = (int)((float)(w1 - w0) / (float)OUT_W);

    int rlo, rhi, clo, chi;
    if (hstep >= 1) {
        rlo = h0 + oi * hstep;
        rhi = (oi < OUT_H - 1) ? (rlo + hstep) : h1;
    } else {
        rlo = (oi == OUT_H - 1) ? h0 : 0;
        rhi = (oi == OUT_H - 1) ? h1 : 0;
    }
    if (wstep >= 1) {
        clo = w0 + oj * wstep;
        chi = (oj < OUT_W - 1) ? (clo + wstep) : w1;
    } else {
        clo = (oj == OUT_W - 1) ? w0 : 0;
        chi = (oj == OUT_W - 1) ? w1 : 0;
    }

    const v4f* base =
        (const v4f*)(fmap + (size_t)b * NH * NW * NC) + lane;
    // pixel (h,w): base[(h*NW + w)*C4]

    const v4f ninf = (v4f){-INFINITY, -INFINITY, -INFINITY, -INFINITY};
    v4f acc0 = ninf, acc1 = ninf, acc2 = ninf, acc3 = ninf;

    // this wave's columns: clo+wid, clo+wid+4, clo+wid+8, ...
    const int wstart = clo + wid;

    int h = rlo;
    for (; h + 1 < rhi; h += 2) {
        const v4f* r0p = base + (size_t)(h * NW) * C4;
        const v4f* r1p = r0p + (size_t)NW * C4;
        int w = wstart;
        for (; w + 4 < chi; w += 8) {
            acc0 = vmax4(acc0, r0p[(size_t)w * C4]);
            acc1 = vmax4(acc1, r0p[(size_t)(w + 4) * C4]);
            acc2 = vmax4(acc2, r1p[(size_t)w * C4]);
            acc3 = vmax4(acc3, r1p[(size_t)(w + 4) * C4]);
        }
        if (w < chi) {
            acc0 = vmax4(acc0, r0p[(size_t)w * C4]);
            acc2 = vmax4(acc2, r1p[(size_t)w * C4]);
        }
    }
    if (h < rhi) {
        const v4f* r0p = base + (size_t)(h * NW) * C4;
        int w = wstart;
        for (; w + 4 < chi; w += 8) {
            acc0 = vmax4(acc0, r0p[(size_t)w * C4]);
            acc1 = vmax4(acc1, r0p[(size_t)(w + 4) * C4]);
        }
        if (w < chi) acc0 = vmax4(acc0, r0p[(size_t)w * C4]);
    }

    v4f acc = vmax4(vmax4(acc0, acc1), vmax4(acc2, acc3));

    if (wid > 0) red[wid - 1][lane] = acc;
    __syncthreads();

    if (wid == 0) {
        acc = vmax4(acc, red[0][lane]);
        acc = vmax4(acc, vmax4(red[1][lane], red[2][lane]));
        const size_t obase = ((size_t)((b * NR + r) * NBIN + bin)) * NC;
        v4f* o = (v4f*)(out + obase);
        __builtin_nontemporal_store(acc, o + lane);
    }
}

extern "C" void kernel_launch(void* const* d_in, const int* in_sizes, int n_in,
                              void* d_out, int out_size, void* d_ws, size_t ws_size,
                              hipStream_t stream) {
    const float* fmap = (const float*)d_in[0];
    const float* rois = (const float*)d_in[1];
    float* out = (float*)d_out;

    const int nblocks = NB * NR * NBIN;   // 12544
    roi_pool_kernel<<<nblocks, 256, 0, stream>>>(fmap, rois, out);
}